// Round 1
// baseline (1231.061 us; speedup 1.0000x reference)
//
#include <hip/hip_runtime.h>

#define B_ 8
#define C_ 64
#define N_ 4096
#define O_ 64
#define E_ 128
#define K_ 20
#define EPS_ 1e-5f

typedef float v2f __attribute__((ext_vector_type(2)));

// ---- workspace layout (float offsets) ----
#define WS_PTS   0                         // (B,N,C)  pts[b][n][c]
#define WS_SQ    (WS_PTS + B_*N_*C_)       // (B,N)    |p|^2
#define WS_Y     (WS_SQ  + B_*N_)          // (B,N,O)  wa . p
#define WS_Z     (WS_Y   + B_*N_*O_)       // (B,N,O)  wb . p
#define WS_M     (WS_Z   + B_*N_*O_)       // (B,O,N)  max-conv output
#define WS_GAMMA (WS_M   + B_*N_*O_)       // (B,O)
#define WS_BETA  (WS_GAMMA + B_*O_)
#define WS_SCALE (WS_BETA  + B_*O_)
#define WS_SHIFT (WS_SCALE + B_*O_)

// ===================== k0: domain MLPs -> gamma/beta =====================
__global__ __launch_bounds__(256) void k0_mlp(const float* __restrict__ emb,
    const float* __restrict__ gw1, const float* __restrict__ gb1,
    const float* __restrict__ gw2, const float* __restrict__ gb2,
    const float* __restrict__ bw1, const float* __restrict__ bb1,
    const float* __restrict__ bw2, const float* __restrict__ bb2,
    float* __restrict__ ws)
{
  __shared__ float s_emb[B_][E_];
  __shared__ float s_h[2][B_][E_];
  int t = threadIdx.x;
  for (int i = t; i < B_*E_; i += 256) s_emb[i >> 7][i & 127] = emb[i];
  __syncthreads();
  {
    int net = t >> 7, e = t & 127;
    const float* w1 = net ? bw1 : gw1;
    const float* b1 = net ? bb1 : gb1;
    float acc[B_];
#pragma unroll
    for (int b = 0; b < B_; ++b) acc[b] = 0.f;
    const float* row = w1 + e * E_;
    for (int j = 0; j < E_; j += 4) {
      float4 w = *(const float4*)(row + j);
#pragma unroll
      for (int b = 0; b < B_; ++b)
        acc[b] += s_emb[b][j]*w.x + s_emb[b][j+1]*w.y + s_emb[b][j+2]*w.z + s_emb[b][j+3]*w.w;
    }
    float bias = b1[e];
#pragma unroll
    for (int b = 0; b < B_; ++b) s_h[net][b][e] = fmaxf(acc[b] + bias, 0.f);
  }
  __syncthreads();
  for (int r = 0; r < 4; ++r) {
    int idx = t + 256 * r;
    int net = idx >> 9, b = (idx >> 6) & 7, o = idx & 63;
    const float* w2 = net ? bw2 : gw2;
    const float* b2 = net ? bb2 : gb2;
    const float* row = w2 + o * E_;
    float acc = 0.f;
    for (int e = 0; e < E_; e += 4) {
      float4 w = *(const float4*)(row + e);
      acc += s_h[net][b][e]*w.x + s_h[net][b][e+1]*w.y + s_h[net][b][e+2]*w.z + s_h[net][b][e+3]*w.w;
    }
    acc += b2[o];
    if (net == 0) ws[WS_GAMMA + b*O_ + o] = 1.f + acc;
    else          ws[WS_BETA  + b*O_ + o] = acc;
  }
}

// ===================== k1a: transpose x -> pts, sq norms =====================
__global__ __launch_bounds__(256) void k1a_transpose(const float* __restrict__ x, float* __restrict__ ws)
{
  __shared__ float T[C_][65];
  __shared__ float sqp[4][C_];
  int b = blockIdx.y, n0 = blockIdx.x * 64;
  int t = threadIdx.x;
  int nl = t & 63, cw = t >> 6;
  float part = 0.f;
#pragma unroll
  for (int k = 0; k < 16; ++k) {
    int c = cw + 4 * k;
    float v = x[((size_t)b * C_ + c) * N_ + n0 + nl];
    T[c][nl] = v;
    part += v * v;
  }
  sqp[cw][nl] = part;
  __syncthreads();
  if (t < 64)
    ws[WS_SQ + b * N_ + n0 + t] = sqp[0][t] + sqp[1][t] + sqp[2][t] + sqp[3][t];
#pragma unroll
  for (int k = 0; k < 16; ++k) {
    int n = cw + 4 * k;
    ws[WS_PTS + ((size_t)b * N_ + n0 + n) * C_ + nl] = T[nl][n];
  }
}

// ===================== k1b: Y = wa.p, Z = wb.p =====================
__global__ __launch_bounds__(256) void k1b_yz(const float* __restrict__ cw_, float* __restrict__ ws)
{
  __shared__ float P[64][65];
  __shared__ float waT[C_][O_];
  __shared__ float wbT[C_][O_];
  int b = blockIdx.y, n0 = blockIdx.x * 64;
  int t = threadIdx.x;
  {
    int o = t & 63, cb = t >> 6;
#pragma unroll
    for (int k = 0; k < 16; ++k) {
      int c = cb + 4 * k;
      float w1v = cw_[o * 128 + c];
      float w2v = cw_[o * 128 + 64 + c];
      waT[c][o] = w1v;
      wbT[c][o] = w2v - w1v;
    }
  }
  {
    int c4 = (t & 15) * 4;
#pragma unroll
    for (int k = 0; k < 4; ++k) {
      int n = (t >> 4) + 16 * k;
      float4 v = *(const float4*)&ws[WS_PTS + ((size_t)b * N_ + n0 + n) * C_ + c4];
      P[n][c4] = v.x; P[n][c4+1] = v.y; P[n][c4+2] = v.z; P[n][c4+3] = v.w;
    }
  }
  __syncthreads();
  int n = t & 63, og = t >> 6;
  v2f accY[8], accZ[8];
  const v2f zero2 = {0.f, 0.f};
#pragma unroll
  for (int i = 0; i < 8; ++i) { accY[i] = zero2; accZ[i] = zero2; }
  for (int c = 0; c < C_; ++c) {
    float p = P[n][c];
    v2f pp = {p, p};
    const v2f* wa2 = (const v2f*)&waT[c][og * 16];
    const v2f* wb2 = (const v2f*)&wbT[c][og * 16];
#pragma unroll
    for (int i = 0; i < 8; ++i) {
      accY[i] = __builtin_elementwise_fma(pp, wa2[i], accY[i]);
      accZ[i] = __builtin_elementwise_fma(pp, wb2[i], accZ[i]);
    }
  }
  size_t baseY = WS_Y + ((size_t)b * N_ + n0 + n) * O_ + og * 16;
  size_t baseZ = WS_Z + ((size_t)b * N_ + n0 + n) * O_ + og * 16;
#pragma unroll
  for (int i = 0; i < 8; ++i) {
    *(float2*)&ws[baseY + 2 * i] = make_float2(accY[i][0], accY[i][1]);
    *(float2*)&ws[baseZ + 2 * i] = make_float2(accZ[i][0], accZ[i][1]);
  }
}

// ===================== k2: fused KNN + gather-max =====================
// LDS carve (bytes):
//   Qt    @ 0       : 64*128*4 = 32768   (c-major, granule-split layout)
//   Pt    @ 32768   : 64*64*4  = 16384   (c-major, rotated granules)
//   Sd    @ 49152   : 128*68*4 = 34816   (dot tile, stride 68, rotated granules)
//   pend  @ 83968   : 256*17*8 = 34816   (per-thread pending candidates)
//   sqm   @ 118784  : 2*64*4   = 512     (double-buffered)
//   fidx  @ 119296  : 128*21*4 = 10752   -> total 130048
//   list2 @ 32768 (overlay Pt+Sd, 43008) ; Mt @ 0 (overlay Qt, 33280)
#define K2_LDS 130048

__global__ __launch_bounds__(256) void k2_knn(float* __restrict__ ws)
{
  extern __shared__ char lds_raw[];
  float*  Qt    = (float*)(lds_raw);
  float*  Pt    = (float*)(lds_raw + 32768);
  float*  Sd    = (float*)(lds_raw + 49152);
  float2* pend  = (float2*)(lds_raw + 83968);
  float*  sqm   = (float*)(lds_raw + 118784);
  int*    fidx  = (int*)(lds_raw + 119296);
  float2* list2 = (float2*)(lds_raw + 32768);
  float*  Mt    = (float*)(lds_raw);

  const int t = threadIdx.x;
  const int b = blockIdx.y;
  const int n0 = blockIdx.x * 128;
  const float* __restrict__ pts = ws + WS_PTS + (size_t)b * N_ * C_;
  const float* __restrict__ sqg = ws + WS_SQ + (size_t)b * N_;

  // ---- stage Qt: element (c,q) -> word 128c + ((q&4)<<4) + ((q>>3)<<2) + (q&3)
  {
    int c = t & 63;
    int qb0 = t >> 6;
#pragma unroll 4
    for (int k = 0; k < 32; ++k) {
      int q = qb0 + 4 * k;
      float v = pts[(size_t)(n0 + q) * C_ + c];
      Qt[128 * c + ((q & 4) << 4) + ((q >> 3) << 2) + (q & 3)] = v;
    }
  }

  // ---- selection state: sorted top-20 (key = |m|^2 - 2*dot, per-query offset dropped)
  float kd[K_]; int ki[K_];
#pragma unroll
  for (int i = 0; i < K_; ++i) { kd[i] = __builtin_inff(); ki[i] = 0; }
  float kd19 = __builtin_inff();
  int cnt = 0;
  const int q_sel = t & 127;
  const int h_sel = t >> 7;
  const int qg = n0 + q_sel;
  const int gbase = h_sel * 8;   // float4-granule base within candidate tile

  const int qi = t >> 4;         // 0..15
  const int cj = t & 15;         // 0..15
  const int q0 = qi * 8;

  auto flush = [&]() {
#pragma unroll 1
    for (int s = 0; s < 17; ++s) {
      if (__all(s >= cnt)) break;
      if (s < cnt) {
        float2 e2 = pend[t * 17 + s];
        float kx = e2.x; int mx = __float_as_int(e2.y);
        if (kx < kd[K_ - 1]) {
          bool cc[K_];
#pragma unroll
          for (int i = 0; i < K_; ++i) cc[i] = kx < kd[i];
#pragma unroll
          for (int i = K_ - 1; i >= 1; --i) {
            kd[i] = cc[i-1] ? kd[i-1] : (cc[i] ? kx : kd[i]);
            ki[i] = cc[i-1] ? ki[i-1] : (cc[i] ? mx : ki[i]);
          }
          kd[0] = cc[0] ? kx : kd[0];
          ki[0] = cc[0] ? mx : ki[0];
        }
      }
    }
    cnt = 0;
    kd19 = kd[K_ - 1];
  };

  __syncthreads();

  for (int ct = 0; ct < 64; ++ct) {
    const int mb = ct * 64;
    // ---- stage Pt (c-major, rotated: word = 64c + ((m+4c)&63)) + sqm
    {
      int c4 = (t & 15) * 4;
      int ml = t >> 4;
#pragma unroll
      for (int k = 0; k < 4; ++k) {
        int m = ml + 16 * k;
        float4 v = *(const float4*)&pts[(size_t)(mb + m) * C_ + c4];
        Pt[64 * c4       + ((m + 4 * c4) & 63)]       = v.x;
        Pt[64 * (c4 + 1) + ((m + 4 * (c4 + 1)) & 63)] = v.y;
        Pt[64 * (c4 + 2) + ((m + 4 * (c4 + 2)) & 63)] = v.z;
        Pt[64 * (c4 + 3) + ((m + 4 * (c4 + 3)) & 63)] = v.w;
      }
      if (t < 64) sqm[(ct & 1) * 64 + t] = sqg[mb + t];
    }
    __syncthreads();
    // ---- GEMM: 128q x 64c tile, micro 8q x 4c, packed-f32 FMA
    {
      v2f acc[4][4];
      const v2f zero2 = {0.f, 0.f};
#pragma unroll
      for (int i = 0; i < 4; ++i)
#pragma unroll
        for (int j = 0; j < 4; ++j) acc[i][j] = zero2;
#pragma unroll 8
      for (int c = 0; c < 64; ++c) {
        float4 qa  = *(float4*)&Qt[128 * c + 4 * qi];
        float4 qb4 = *(float4*)&Qt[128 * c + 64 + 4 * qi];
        float4 pv  = *(float4*)&Pt[64 * c + 4 * ((cj + c) & 15)];
        v2f qp[4] = { {qa.x, qa.y}, {qa.z, qa.w}, {qb4.x, qb4.y}, {qb4.z, qb4.w} };
        float pe[4] = { pv.x, pv.y, pv.z, pv.w };
#pragma unroll
        for (int j = 0; j < 4; ++j) {
          v2f pj = { pe[j], pe[j] };
#pragma unroll
          for (int i = 0; i < 4; ++i)
            acc[i][j] = __builtin_elementwise_fma(qp[i], pj, acc[i][j]);
        }
      }
#pragma unroll
      for (int r = 0; r < 8; ++r) {
        int q = q0 + r;
        float4 o4;
        o4.x = acc[r >> 1][0][r & 1];
        o4.y = acc[r >> 1][1][r & 1];
        o4.z = acc[r >> 1][2][r & 1];
        o4.w = acc[r >> 1][3][r & 1];
        *(float4*)&Sd[68 * q + 4 * ((cj + 2 * q) & 15)] = o4;
      }
    }
    __syncthreads();
    // ---- scan 32 candidates (this thread's half) with batched top-k maintenance
    {
      const float* sq_t = &sqm[(ct & 1) * 64];
#pragma unroll
      for (int g4 = 0; g4 < 8; ++g4) {
        int g = gbase + g4;
        float4 d4 = *(float4*)&Sd[68 * q_sel + 4 * ((g + 2 * q_sel) & 15)];
        float dv[4] = { d4.x, d4.y, d4.z, d4.w };
#pragma unroll
        for (int e = 0; e < 4; ++e) {
          int j = g * 4 + e;
          int m = mb + j;
          float key = sq_t[j] - 2.f * dv[e];
          if ((key < kd19) & (m != qg)) {
            pend[t * 17 + cnt] = make_float2(key, __int_as_float(m));
            ++cnt;
          }
        }
        if (__any(cnt >= 14)) flush();
      }
    }
  }
  flush();
  __syncthreads();
  // ---- write sorted half-lists, merge halves -> final 20 indices
#pragma unroll
  for (int s = 0; s < K_; ++s) list2[t * 21 + s] = make_float2(kd[s], __int_as_float(ki[s]));
  __syncthreads();
  if (t < 128) {
    int ia = 0, ib2 = 0;
#pragma unroll 1
    for (int k = 0; k < K_; ++k) {
      float2 fa = list2[t * 21 + ia];
      float2 fb = list2[(t + 128) * 21 + ib2];
      bool ta = fa.x <= fb.x;
      fidx[t * 21 + k] = __float_as_int(ta ? fa.y : fb.y);
      ia += ta ? 1 : 0; ib2 += ta ? 0 : 1;
    }
  }
  __syncthreads();
  // ---- gather-max epilogue: M[b][o][n] = max_k Y[b][nbr][o] + Z[b][n][o]
  {
    int q = t & 127;
    int ob = (t >> 7) * 32;
    const float* __restrict__ Yb = ws + WS_Y + (size_t)b * N_ * O_;
    float4 mx[8];
#pragma unroll
    for (int i = 0; i < 8; ++i)
      mx[i] = make_float4(-__builtin_inff(), -__builtin_inff(), -__builtin_inff(), -__builtin_inff());
#pragma unroll 1
    for (int k = 0; k < K_; ++k) {
      int m = fidx[q * 21 + k];
      const float4* yr = (const float4*)&Yb[(size_t)m * O_ + ob];
#pragma unroll
      for (int i = 0; i < 8; ++i) {
        float4 v = yr[i];
        mx[i].x = fmaxf(mx[i].x, v.x);
        mx[i].y = fmaxf(mx[i].y, v.y);
        mx[i].z = fmaxf(mx[i].z, v.z);
        mx[i].w = fmaxf(mx[i].w, v.w);
      }
    }
    const float4* zr = (const float4*)&ws[WS_Z + ((size_t)b * N_ + n0 + q) * O_ + ob];
#pragma unroll
    for (int i = 0; i < 8; ++i) {
      float4 z = zr[i];
      Mt[q * 65 + ob + 4 * i + 0] = mx[i].x + z.x;
      Mt[q * 65 + ob + 4 * i + 1] = mx[i].y + z.y;
      Mt[q * 65 + ob + 4 * i + 2] = mx[i].z + z.z;
      Mt[q * 65 + ob + 4 * i + 3] = mx[i].w + z.w;
    }
  }
  __syncthreads();
  // ---- transpose-write M to (B,O,N)
  {
    int o = t >> 2, qp = (t & 3) * 32;
    float* Mrow = ws + WS_M + ((size_t)b * O_ + o) * N_ + n0 + qp;
#pragma unroll
    for (int i = 0; i < 32; i += 4) {
      float4 w;
      w.x = Mt[(qp + i + 0) * 65 + o];
      w.y = Mt[(qp + i + 1) * 65 + o];
      w.z = Mt[(qp + i + 2) * 65 + o];
      w.w = Mt[(qp + i + 3) * 65 + o];
      *(float4*)&Mrow[i] = w;
    }
  }
}

// ===================== k3: per-(b,o) mean/var -> scale/shift =====================
__global__ __launch_bounds__(256) void k3_stats(float* __restrict__ ws)
{
  int bo = blockIdx.x;
  int t = threadIdx.x;
  const float4* Mr = (const float4*)&ws[WS_M + (size_t)bo * N_];
  float s = 0.f, ss = 0.f;
#pragma unroll
  for (int k = 0; k < 4; ++k) {
    float4 v = Mr[t + 256 * k];
    s  += v.x + v.y + v.z + v.w;
    ss += v.x * v.x + v.y * v.y + v.z * v.z + v.w * v.w;
  }
#pragma unroll
  for (int off = 32; off >= 1; off >>= 1) {
    s  += __shfl_down(s, off);
    ss += __shfl_down(ss, off);
  }
  __shared__ float red[8];
  int w = t >> 6;
  if ((t & 63) == 0) { red[w * 2] = s; red[w * 2 + 1] = ss; }
  __syncthreads();
  if (t == 0) {
    float S  = red[0] + red[2] + red[4] + red[6];
    float SS = red[1] + red[3] + red[5] + red[7];
    float mean = S / (float)N_;
    float var = fmaxf(SS / (float)N_ - mean * mean, 0.f);
    float g  = ws[WS_GAMMA + bo];
    float be = ws[WS_BETA + bo];
    float sc = g / sqrtf(var + EPS_);
    ws[WS_SCALE + bo] = sc;
    ws[WS_SHIFT + bo] = be - mean * sc;
  }
}

// ===================== k4: normalize + affine + relu =====================
__global__ __launch_bounds__(256) void k4_apply(const float* __restrict__ ws, float* __restrict__ out)
{
  int i4 = blockIdx.x * 256 + threadIdx.x;
  int bo = i4 >> 10;
  float sc = ws[WS_SCALE + bo], sh = ws[WS_SHIFT + bo];
  float4 v = *(const float4*)&ws[WS_M + (size_t)i4 * 4];
  float4 r;
  r.x = fmaxf(fmaf(v.x, sc, sh), 0.f);
  r.y = fmaxf(fmaf(v.y, sc, sh), 0.f);
  r.z = fmaxf(fmaf(v.z, sc, sh), 0.f);
  r.w = fmaxf(fmaf(v.w, sc, sh), 0.f);
  *(float4*)&out[(size_t)i4 * 4] = r;
}

extern "C" void kernel_launch(void* const* d_in, const int* in_sizes, int n_in,
                              void* d_out, int out_size, void* d_ws, size_t ws_size,
                              hipStream_t stream)
{
  const float* x   = (const float*)d_in[0];
  const float* emb = (const float*)d_in[1];
  const float* cw  = (const float*)d_in[2];
  const float* gw1 = (const float*)d_in[3];
  const float* gb1 = (const float*)d_in[4];
  const float* gw2 = (const float*)d_in[5];
  const float* gb2 = (const float*)d_in[6];
  const float* bw1 = (const float*)d_in[7];
  const float* bb1 = (const float*)d_in[8];
  const float* bw2 = (const float*)d_in[9];
  const float* bb2 = (const float*)d_in[10];
  float* ws  = (float*)d_ws;
  float* out = (float*)d_out;

  k0_mlp<<<1, 256, 0, stream>>>(emb, gw1, gb1, gw2, gb2, bw1, bb1, bw2, bb2, ws);
  k1a_transpose<<<dim3(64, 8), 256, 0, stream>>>(x, ws);
  k1b_yz<<<dim3(64, 8), 256, 0, stream>>>(cw, ws);
  k2_knn<<<dim3(32, 8), 256, K2_LDS, stream>>>(ws);
  k3_stats<<<512, 256, 0, stream>>>(ws);
  k4_apply<<<2048, 256, 0, stream>>>(ws, out);
}

// Round 2
// 900.113 us; speedup vs baseline: 1.3677x; 1.3677x over previous
//
#include <hip/hip_runtime.h>

#define B_ 8
#define C_ 64
#define N_ 4096
#define O_ 64
#define E_ 128
#define K_ 20
#define EPS_ 1e-5f

typedef float v2f __attribute__((ext_vector_type(2)));

// ---- workspace layout (float offsets) ----
#define WS_PTS   0                         // (B,N,C)  pts[b][n][c]
#define WS_SQ    (WS_PTS + B_*N_*C_)       // (B,N)    |p|^2
#define WS_Y     (WS_SQ  + B_*N_)          // (B,N,O)  wa . p
#define WS_Z     (WS_Y   + B_*N_*O_)       // (B,N,O)  wb . p
#define WS_M     (WS_Z   + B_*N_*O_)       // (B,O,N)  max-conv output
#define WS_GAMMA (WS_M   + B_*N_*O_)       // (B,O)
#define WS_BETA  (WS_GAMMA + B_*O_)
#define WS_SCALE (WS_BETA  + B_*O_)
#define WS_SHIFT (WS_SCALE + B_*O_)

// ===================== k0: domain MLPs -> gamma/beta =====================
__global__ __launch_bounds__(256) void k0_mlp(const float* __restrict__ emb,
    const float* __restrict__ gw1, const float* __restrict__ gb1,
    const float* __restrict__ gw2, const float* __restrict__ gb2,
    const float* __restrict__ bw1, const float* __restrict__ bb1,
    const float* __restrict__ bw2, const float* __restrict__ bb2,
    float* __restrict__ ws)
{
  __shared__ float s_emb[B_][E_];
  __shared__ float s_h[2][B_][E_];
  int t = threadIdx.x;
  for (int i = t; i < B_*E_; i += 256) s_emb[i >> 7][i & 127] = emb[i];
  __syncthreads();
  {
    int net = t >> 7, e = t & 127;
    const float* w1 = net ? bw1 : gw1;
    const float* b1 = net ? bb1 : gb1;
    float acc[B_];
#pragma unroll
    for (int b = 0; b < B_; ++b) acc[b] = 0.f;
    const float* row = w1 + e * E_;
    for (int j = 0; j < E_; j += 4) {
      float4 w = *(const float4*)(row + j);
#pragma unroll
      for (int b = 0; b < B_; ++b)
        acc[b] += s_emb[b][j]*w.x + s_emb[b][j+1]*w.y + s_emb[b][j+2]*w.z + s_emb[b][j+3]*w.w;
    }
    float bias = b1[e];
#pragma unroll
    for (int b = 0; b < B_; ++b) s_h[net][b][e] = fmaxf(acc[b] + bias, 0.f);
  }
  __syncthreads();
  for (int r = 0; r < 4; ++r) {
    int idx = t + 256 * r;
    int net = idx >> 9, b = (idx >> 6) & 7, o = idx & 63;
    const float* w2 = net ? bw2 : gw2;
    const float* b2 = net ? bb2 : gb2;
    const float* row = w2 + o * E_;
    float acc = 0.f;
    for (int e = 0; e < E_; e += 4) {
      float4 w = *(const float4*)(row + e);
      acc += s_h[net][b][e]*w.x + s_h[net][b][e+1]*w.y + s_h[net][b][e+2]*w.z + s_h[net][b][e+3]*w.w;
    }
    acc += b2[o];
    if (net == 0) ws[WS_GAMMA + b*O_ + o] = 1.f + acc;
    else          ws[WS_BETA  + b*O_ + o] = acc;
  }
}

// ===================== k1a: transpose x -> pts, sq norms =====================
__global__ __launch_bounds__(256) void k1a_transpose(const float* __restrict__ x, float* __restrict__ ws)
{
  __shared__ float T[C_][65];
  __shared__ float sqp[4][C_];
  int b = blockIdx.y, n0 = blockIdx.x * 64;
  int t = threadIdx.x;
  int nl = t & 63, cw = t >> 6;
  float part = 0.f;
#pragma unroll
  for (int k = 0; k < 16; ++k) {
    int c = cw + 4 * k;
    float v = x[((size_t)b * C_ + c) * N_ + n0 + nl];
    T[c][nl] = v;
    part += v * v;
  }
  sqp[cw][nl] = part;
  __syncthreads();
  if (t < 64)
    ws[WS_SQ + b * N_ + n0 + t] = sqp[0][t] + sqp[1][t] + sqp[2][t] + sqp[3][t];
#pragma unroll
  for (int k = 0; k < 16; ++k) {
    int n = cw + 4 * k;
    ws[WS_PTS + ((size_t)b * N_ + n0 + n) * C_ + nl] = T[nl][n];
  }
}

// ===================== k1b: Y = wa.p, Z = wb.p =====================
__global__ __launch_bounds__(256) void k1b_yz(const float* __restrict__ cw_, float* __restrict__ ws)
{
  __shared__ float P[64][65];
  __shared__ float waT[C_][O_];
  __shared__ float wbT[C_][O_];
  int b = blockIdx.y, n0 = blockIdx.x * 64;
  int t = threadIdx.x;
  {
    int o = t & 63, cb = t >> 6;
#pragma unroll
    for (int k = 0; k < 16; ++k) {
      int c = cb + 4 * k;
      float w1v = cw_[o * 128 + c];
      float w2v = cw_[o * 128 + 64 + c];
      waT[c][o] = w1v;
      wbT[c][o] = w2v - w1v;
    }
  }
  {
    int c4 = (t & 15) * 4;
#pragma unroll
    for (int k = 0; k < 4; ++k) {
      int n = (t >> 4) + 16 * k;
      float4 v = *(const float4*)&ws[WS_PTS + ((size_t)b * N_ + n0 + n) * C_ + c4];
      P[n][c4] = v.x; P[n][c4+1] = v.y; P[n][c4+2] = v.z; P[n][c4+3] = v.w;
    }
  }
  __syncthreads();
  int n = t & 63, og = t >> 6;
  v2f accY[8], accZ[8];
  const v2f zero2 = {0.f, 0.f};
#pragma unroll
  for (int i = 0; i < 8; ++i) { accY[i] = zero2; accZ[i] = zero2; }
  for (int c = 0; c < C_; ++c) {
    float p = P[n][c];
    v2f pp = {p, p};
    const v2f* wa2 = (const v2f*)&waT[c][og * 16];
    const v2f* wb2 = (const v2f*)&wbT[c][og * 16];
#pragma unroll
    for (int i = 0; i < 8; ++i) {
      accY[i] = __builtin_elementwise_fma(pp, wa2[i], accY[i]);
      accZ[i] = __builtin_elementwise_fma(pp, wb2[i], accZ[i]);
    }
  }
  size_t baseY = WS_Y + ((size_t)b * N_ + n0 + n) * O_ + og * 16;
  size_t baseZ = WS_Z + ((size_t)b * N_ + n0 + n) * O_ + og * 16;
#pragma unroll
  for (int i = 0; i < 8; ++i) {
    *(float2*)&ws[baseY + 2 * i] = make_float2(accY[i][0], accY[i][1]);
    *(float2*)&ws[baseZ + 2 * i] = make_float2(accZ[i][0], accZ[i][1]);
  }
}

// ===================== k2: fused KNN + gather-max (512 threads) =====================
// Main-phase LDS (bytes):
//   Qt   @ 0      : 64c x 128q  = 32768   word = 128c + q
//   Pt   @ 32768  : 64c x 128m  = 32768   word = 128c + m
//   Sd   @ 65536  : 128q x 128m = 65536   word = 128q + (4*m4 ^ ((q&7)<<2)) + (m&3)
//   pend @ 131072 : 512*7*8     = 28672
//   sqm  @ 159744 : 2*128*4     = 1024    -> total 160768 (<=163840, 1 blk/CU, 8 waves)
// Final-phase overlays: list2@0 (86016), lmrg@90112 (43008), fidx@135168 (10752), Mt@0 (33280)
#define K2_LDS 160768

__device__ __forceinline__ int SDW(int q, int m4) {
  return q * 128 + ((4 * m4) ^ ((q & 7) << 2));
}

__global__ __launch_bounds__(512, 2) void k2_knn(float* __restrict__ ws)
{
  extern __shared__ char lds_raw[];
  float*  Qt    = (float*)(lds_raw);
  float*  Pt    = (float*)(lds_raw + 32768);
  float*  Sd    = (float*)(lds_raw + 65536);
  float2* pend  = (float2*)(lds_raw + 131072);
  float*  sqm   = (float*)(lds_raw + 159744);
  float2* list2 = (float2*)(lds_raw);
  float2* lmrg  = (float2*)(lds_raw + 90112);
  int*    fidx  = (int*)(lds_raw + 135168);
  float*  Mt    = (float*)(lds_raw);

  const int t = threadIdx.x;
  const int b = blockIdx.y;
  const int n0 = blockIdx.x * 128;
  const float* __restrict__ pts = ws + WS_PTS + (size_t)b * N_ * C_;
  const float* __restrict__ sqg = ws + WS_SQ + (size_t)b * N_;

  // ---- stage Qt: thread q = t&127 loads its row (4 x float4), writes c-major
  {
    int q = t & 127, c0 = (t >> 7) * 16;
    const float* src = &pts[(size_t)(n0 + q) * C_ + c0];
    float4 v0 = *(const float4*)(src + 0);
    float4 v1 = *(const float4*)(src + 4);
    float4 v2 = *(const float4*)(src + 8);
    float4 v3 = *(const float4*)(src + 12);
    Qt[(c0+ 0)*128 + q] = v0.x; Qt[(c0+ 1)*128 + q] = v0.y; Qt[(c0+ 2)*128 + q] = v0.z; Qt[(c0+ 3)*128 + q] = v0.w;
    Qt[(c0+ 4)*128 + q] = v1.x; Qt[(c0+ 5)*128 + q] = v1.y; Qt[(c0+ 6)*128 + q] = v1.z; Qt[(c0+ 7)*128 + q] = v1.w;
    Qt[(c0+ 8)*128 + q] = v2.x; Qt[(c0+ 9)*128 + q] = v2.y; Qt[(c0+10)*128 + q] = v2.z; Qt[(c0+11)*128 + q] = v2.w;
    Qt[(c0+12)*128 + q] = v3.x; Qt[(c0+13)*128 + q] = v3.y; Qt[(c0+14)*128 + q] = v3.z; Qt[(c0+15)*128 + q] = v3.w;
  }

  // ---- selection state: sorted top-20 (key = |m|^2 - 2*dot)
  float kd[K_]; int ki[K_];
#pragma unroll
  for (int i = 0; i < K_; ++i) { kd[i] = __builtin_inff(); ki[i] = 0; }
  float kd19 = __builtin_inff();
  int cnt = 0;
  const int q_sel = t & 127;
  const int quarter = t >> 7;          // 0..3
  const int gbase = quarter * 8;       // float4-granule base (0..31 total)
  const int qg = n0 + q_sel;

  const int qi = t >> 5;               // 0..15 -> 8-query block
  const int mj = t & 31;               // 0..31 -> float4 m-group

  auto flush = [&]() {
#pragma unroll 1
    for (int s = 0; s < 7; ++s) {
      if (__all(s >= cnt)) break;
      if (s < cnt) {
        float2 e2 = pend[t * 7 + s];
        float kx = e2.x; int mx = __float_as_int(e2.y);
        if (kx < kd[K_ - 1]) {
          bool cc[K_];
#pragma unroll
          for (int i = 0; i < K_; ++i) cc[i] = kx < kd[i];
#pragma unroll
          for (int i = K_ - 1; i >= 1; --i) {
            kd[i] = cc[i-1] ? kd[i-1] : (cc[i] ? kx : kd[i]);
            ki[i] = cc[i-1] ? ki[i-1] : (cc[i] ? mx : ki[i]);
          }
          kd[0] = cc[0] ? kx : kd[0];
          ki[0] = cc[0] ? mx : ki[0];
        }
      }
    }
    cnt = 0;
    kd19 = kd[K_ - 1];
  };

  __syncthreads();

  for (int ct = 0; ct < 32; ++ct) {
    const int mb = ct * 128;
    // ---- stage Pt: thread m = t&127 loads its row, writes c-major (bank = m%32, 2-way)
    {
      int m = t & 127, c0 = (t >> 7) * 16;
      const float* src = &pts[(size_t)(mb + m) * C_ + c0];
      float4 v0 = *(const float4*)(src + 0);
      float4 v1 = *(const float4*)(src + 4);
      float4 v2 = *(const float4*)(src + 8);
      float4 v3 = *(const float4*)(src + 12);
      Pt[(c0+ 0)*128 + m] = v0.x; Pt[(c0+ 1)*128 + m] = v0.y; Pt[(c0+ 2)*128 + m] = v0.z; Pt[(c0+ 3)*128 + m] = v0.w;
      Pt[(c0+ 4)*128 + m] = v1.x; Pt[(c0+ 5)*128 + m] = v1.y; Pt[(c0+ 6)*128 + m] = v1.z; Pt[(c0+ 7)*128 + m] = v1.w;
      Pt[(c0+ 8)*128 + m] = v2.x; Pt[(c0+ 9)*128 + m] = v2.y; Pt[(c0+10)*128 + m] = v2.z; Pt[(c0+11)*128 + m] = v2.w;
      Pt[(c0+12)*128 + m] = v3.x; Pt[(c0+13)*128 + m] = v3.y; Pt[(c0+14)*128 + m] = v3.z; Pt[(c0+15)*128 + m] = v3.w;
      if (t < 128) sqm[(ct & 1) * 128 + t] = sqg[mb + t];
    }
    __syncthreads();
    // ---- GEMM: 128q x 128m tile, micro 8q x 4m, packed-f32 FMA
    {
      v2f acc[4][4];
      const v2f zero2 = {0.f, 0.f};
#pragma unroll
      for (int i = 0; i < 4; ++i)
#pragma unroll
        for (int j = 0; j < 4; ++j) acc[i][j] = zero2;
#pragma unroll 8
      for (int c = 0; c < 64; ++c) {
        float4 qa  = *(float4*)&Qt[128 * c + 8 * qi];
        float4 qb4 = *(float4*)&Qt[128 * c + 8 * qi + 4];
        float4 pv  = *(float4*)&Pt[128 * c + 4 * mj];
        v2f qp[4] = { {qa.x, qa.y}, {qa.z, qa.w}, {qb4.x, qb4.y}, {qb4.z, qb4.w} };
        float pe[4] = { pv.x, pv.y, pv.z, pv.w };
#pragma unroll
        for (int j = 0; j < 4; ++j) {
          v2f pj = { pe[j], pe[j] };
#pragma unroll
          for (int i = 0; i < 4; ++i)
            acc[i][j] = __builtin_elementwise_fma(qp[i], pj, acc[i][j]);
        }
      }
#pragma unroll
      for (int r = 0; r < 8; ++r) {
        int q = 8 * qi + r;
        float4 o4;
        o4.x = acc[r >> 1][0][r & 1];
        o4.y = acc[r >> 1][1][r & 1];
        o4.z = acc[r >> 1][2][r & 1];
        o4.w = acc[r >> 1][3][r & 1];
        *(float4*)&Sd[SDW(q, mj)] = o4;
      }
    }
    __syncthreads();
    // ---- scan this thread's 32 candidates with batched top-k maintenance
    {
      const float* sq_t = &sqm[(ct & 1) * 128];
#pragma unroll
      for (int g4 = 0; g4 < 8; ++g4) {
        int g = gbase + g4;
        float4 d4 = *(float4*)&Sd[SDW(q_sel, g)];
        float dv[4] = { d4.x, d4.y, d4.z, d4.w };
#pragma unroll
        for (int e = 0; e < 4; ++e) {
          int j = g * 4 + e;
          int m = mb + j;
          float key = sq_t[j] - 2.f * dv[e];
          if ((key < kd19) & (m != qg)) {
            pend[t * 7 + cnt] = make_float2(key, __int_as_float(m));
            ++cnt;
          }
        }
        if (__any(cnt >= 4)) flush();
      }
    }
  }
  flush();
  __syncthreads();
  // ---- write sorted quarter-lists
#pragma unroll
  for (int s = 0; s < K_; ++s) list2[(size_t)t * 21 + s] = make_float2(kd[s], __int_as_float(ki[s]));
  __syncthreads();
  // ---- merge stage 1: (L0,L1)->H0, (L2,L3)->H1
  if (t < 256) {
    int q = t & 127, h = t >> 7;
    const float2* la = &list2[(size_t)(q + 256 * h) * 21];
    const float2* lb = &list2[(size_t)(q + 256 * h + 128) * 21];
    float2* lo = &lmrg[(size_t)(q + 128 * h) * 21];
    int ia = 0, ib2 = 0;
#pragma unroll 1
    for (int k = 0; k < K_; ++k) {
      float2 fa = la[ia];
      float2 fb = lb[ib2];
      bool ta = fa.x <= fb.x;
      lo[k] = ta ? fa : fb;
      ia += ta ? 1 : 0; ib2 += ta ? 0 : 1;
    }
  }
  __syncthreads();
  // ---- merge stage 2: H0+H1 -> final 20 indices
  if (t < 128) {
    const float2* la = &lmrg[(size_t)t * 21];
    const float2* lb = &lmrg[(size_t)(t + 128) * 21];
    int ia = 0, ib2 = 0;
#pragma unroll 1
    for (int k = 0; k < K_; ++k) {
      float2 fa = la[ia];
      float2 fb = lb[ib2];
      bool ta = fa.x <= fb.x;
      fidx[t * 21 + k] = __float_as_int(ta ? fa.y : fb.y);
      ia += ta ? 1 : 0; ib2 += ta ? 0 : 1;
    }
  }
  __syncthreads();
  // ---- gather-max epilogue: M[b][o][n] = max_k Y[b][nbr][o] + Z[b][n][o]
  {
    int q = t & 127;
    int ob = (t >> 7) * 16;
    const float* __restrict__ Yb = ws + WS_Y + (size_t)b * N_ * O_;
    float4 mx[4];
#pragma unroll
    for (int i = 0; i < 4; ++i)
      mx[i] = make_float4(-__builtin_inff(), -__builtin_inff(), -__builtin_inff(), -__builtin_inff());
#pragma unroll 1
    for (int k = 0; k < K_; ++k) {
      int m = fidx[q * 21 + k];
      const float4* yr = (const float4*)&Yb[(size_t)m * O_ + ob];
#pragma unroll
      for (int i = 0; i < 4; ++i) {
        float4 v = yr[i];
        mx[i].x = fmaxf(mx[i].x, v.x);
        mx[i].y = fmaxf(mx[i].y, v.y);
        mx[i].z = fmaxf(mx[i].z, v.z);
        mx[i].w = fmaxf(mx[i].w, v.w);
      }
    }
    const float4* zr = (const float4*)&ws[WS_Z + ((size_t)b * N_ + n0 + q) * O_ + ob];
#pragma unroll
    for (int i = 0; i < 4; ++i) {
      float4 z = zr[i];
      Mt[q * 65 + ob + 4 * i + 0] = mx[i].x + z.x;
      Mt[q * 65 + ob + 4 * i + 1] = mx[i].y + z.y;
      Mt[q * 65 + ob + 4 * i + 2] = mx[i].z + z.z;
      Mt[q * 65 + ob + 4 * i + 3] = mx[i].w + z.w;
    }
  }
  __syncthreads();
  // ---- transpose-write M to (B,O,N)
  {
    int o = t >> 3, seg = (t & 7) * 16;
    float* Mrow = ws + WS_M + ((size_t)b * O_ + o) * N_ + n0 + seg;
#pragma unroll
    for (int i = 0; i < 16; i += 4) {
      float4 w;
      w.x = Mt[(seg + i + 0) * 65 + o];
      w.y = Mt[(seg + i + 1) * 65 + o];
      w.z = Mt[(seg + i + 2) * 65 + o];
      w.w = Mt[(seg + i + 3) * 65 + o];
      *(float4*)&Mrow[i] = w;
    }
  }
}

// ===================== k3: per-(b,o) mean/var -> scale/shift =====================
__global__ __launch_bounds__(256) void k3_stats(float* __restrict__ ws)
{
  int bo = blockIdx.x;
  int t = threadIdx.x;
  const float4* Mr = (const float4*)&ws[WS_M + (size_t)bo * N_];
  float s = 0.f, ss = 0.f;
#pragma unroll
  for (int k = 0; k < 4; ++k) {
    float4 v = Mr[t + 256 * k];
    s  += v.x + v.y + v.z + v.w;
    ss += v.x * v.x + v.y * v.y + v.z * v.z + v.w * v.w;
  }
#pragma unroll
  for (int off = 32; off >= 1; off >>= 1) {
    s  += __shfl_down(s, off);
    ss += __shfl_down(ss, off);
  }
  __shared__ float red[8];
  int w = t >> 6;
  if ((t & 63) == 0) { red[w * 2] = s; red[w * 2 + 1] = ss; }
  __syncthreads();
  if (t == 0) {
    float S  = red[0] + red[2] + red[4] + red[6];
    float SS = red[1] + red[3] + red[5] + red[7];
    float mean = S / (float)N_;
    float var = fmaxf(SS / (float)N_ - mean * mean, 0.f);
    float g  = ws[WS_GAMMA + bo];
    float be = ws[WS_BETA + bo];
    float sc = g / sqrtf(var + EPS_);
    ws[WS_SCALE + bo] = sc;
    ws[WS_SHIFT + bo] = be - mean * sc;
  }
}

// ===================== k4: normalize + affine + relu =====================
__global__ __launch_bounds__(256) void k4_apply(const float* __restrict__ ws, float* __restrict__ out)
{
  int i4 = blockIdx.x * 256 + threadIdx.x;
  int bo = i4 >> 10;
  float sc = ws[WS_SCALE + bo], sh = ws[WS_SHIFT + bo];
  float4 v = *(const float4*)&ws[WS_M + (size_t)i4 * 4];
  float4 r;
  r.x = fmaxf(fmaf(v.x, sc, sh), 0.f);
  r.y = fmaxf(fmaf(v.y, sc, sh), 0.f);
  r.z = fmaxf(fmaf(v.z, sc, sh), 0.f);
  r.w = fmaxf(fmaf(v.w, sc, sh), 0.f);
  *(float4*)&out[(size_t)i4 * 4] = r;
}

extern "C" void kernel_launch(void* const* d_in, const int* in_sizes, int n_in,
                              void* d_out, int out_size, void* d_ws, size_t ws_size,
                              hipStream_t stream)
{
  const float* x   = (const float*)d_in[0];
  const float* emb = (const float*)d_in[1];
  const float* cw  = (const float*)d_in[2];
  const float* gw1 = (const float*)d_in[3];
  const float* gb1 = (const float*)d_in[4];
  const float* gw2 = (const float*)d_in[5];
  const float* gb2 = (const float*)d_in[6];
  const float* bw1 = (const float*)d_in[7];
  const float* bb1 = (const float*)d_in[8];
  const float* bw2 = (const float*)d_in[9];
  const float* bb2 = (const float*)d_in[10];
  float* ws  = (float*)d_ws;
  float* out = (float*)d_out;

  k0_mlp<<<1, 256, 0, stream>>>(emb, gw1, gb1, gw2, gb2, bw1, bb1, bw2, bb2, ws);
  k1a_transpose<<<dim3(64, 8), 256, 0, stream>>>(x, ws);
  k1b_yz<<<dim3(64, 8), 256, 0, stream>>>(cw, ws);
  k2_knn<<<dim3(32, 8), 512, K2_LDS, stream>>>(ws);
  k3_stats<<<512, 256, 0, stream>>>(ws);
  k4_apply<<<2048, 256, 0, stream>>>(ws, out);
}

// Round 5
// 802.684 us; speedup vs baseline: 1.5337x; 1.1214x over previous
//
#include <hip/hip_runtime.h>

#define B_ 8
#define C_ 64
#define N_ 4096
#define O_ 64
#define E_ 128
#define K_ 20
#define EPS_ 1e-5f

typedef float v2f __attribute__((ext_vector_type(2)));
typedef __attribute__((ext_vector_type(4)))  int  i32x4;
typedef __attribute__((ext_vector_type(16))) int  i32x16;
typedef __attribute__((ext_vector_type(16))) char c16;

// ---- workspace layout (float offsets) ----
#define WS_SQ    0                          // (B,N) |p_quant|^2 fp32
#define WS_Y     32768                      // (B,N,O)
#define WS_Z     (WS_Y + B_*N_*O_)          // (B,N,O)
#define WS_M     (WS_Z + B_*N_*O_)          // (B,O,N)
#define WS_GAMMA (WS_M + B_*N_*O_)
#define WS_BETA  (WS_GAMMA + 512)
#define WS_SCALE (WS_BETA + 512)
#define WS_SHIFT (WS_SCALE + 512)
#define WS_END_F (WS_SHIFT + 512)
#define WS_I8B   (WS_END_F * 4)             // BYTE offset of i8 limb blobs
// blob per (b,tile): 16384 B = 3 planes x (64 rows x 80 B) + 1024 pad
// plane p, row r, channel c: byte p*5120 + r*80 + (c>>4)*16 + (c&15)

__device__ __forceinline__ void gload16(const void* g, void* l) {
  __builtin_amdgcn_global_load_lds((const __attribute__((address_space(1))) unsigned int*)g,
                                   (__attribute__((address_space(3))) unsigned int*)l, 16, 0, 0);
}

// ===================== k0: domain MLPs -> gamma/beta =====================
__global__ __launch_bounds__(256) void k0_mlp(const float* __restrict__ emb,
    const float* __restrict__ gw1, const float* __restrict__ gb1,
    const float* __restrict__ gw2, const float* __restrict__ gb2,
    const float* __restrict__ bw1, const float* __restrict__ bb1,
    const float* __restrict__ bw2, const float* __restrict__ bb2,
    float* __restrict__ ws)
{
  __shared__ float s_emb[B_][E_];
  __shared__ float s_h[2][B_][E_];
  int t = threadIdx.x;
  for (int i = t; i < B_*E_; i += 256) s_emb[i >> 7][i & 127] = emb[i];
  __syncthreads();
  {
    int net = t >> 7, e = t & 127;
    const float* w1 = net ? bw1 : gw1;
    const float* b1 = net ? bb1 : gb1;
    float acc[B_];
#pragma unroll
    for (int b = 0; b < B_; ++b) acc[b] = 0.f;
    const float* row = w1 + e * E_;
    for (int j = 0; j < E_; j += 4) {
      float4 w = *(const float4*)(row + j);
#pragma unroll
      for (int b = 0; b < B_; ++b)
        acc[b] += s_emb[b][j]*w.x + s_emb[b][j+1]*w.y + s_emb[b][j+2]*w.z + s_emb[b][j+3]*w.w;
    }
    float bias = b1[e];
#pragma unroll
    for (int b = 0; b < B_; ++b) s_h[net][b][e] = fmaxf(acc[b] + bias, 0.f);
  }
  __syncthreads();
  for (int r = 0; r < 4; ++r) {
    int idx = t + 256 * r;
    int net = idx >> 9, b = (idx >> 6) & 7, o = idx & 63;
    const float* w2 = net ? bw2 : gw2;
    const float* b2 = net ? bb2 : gb2;
    const float* row = w2 + o * E_;
    float acc = 0.f;
    for (int e = 0; e < E_; e += 4) {
      float4 w = *(const float4*)(row + e);
      acc += s_h[net][b][e]*w.x + s_h[net][b][e+1]*w.y + s_h[net][b][e+2]*w.z + s_h[net][b][e+3]*w.w;
    }
    acc += b2[o];
    if (net == 0) ws[WS_GAMMA + b*O_ + o] = 1.f + acc;
    else          ws[WS_BETA  + b*O_ + o] = acc;
  }
}

// ===================== k1a: quantize x -> 3 i8 limb planes + exact |p|^2 ====
__global__ __launch_bounds__(256) void k1a_split(const float* __restrict__ x, float* __restrict__ ws)
{
  __shared__ double sqp[4][64];
  int b = blockIdx.y, T = blockIdx.x, n0 = T * 64;
  int t = threadIdx.x;
  int r = t & 63, qc = t >> 6;
  char* blob = (char*)ws + WS_I8B + (size_t)(b * 64 + T) * 16384;
  c16 v0, v1, v2;
  double sq = 0.0;
#pragma unroll
  for (int e = 0; e < 16; ++e) {
    int c = qc * 16 + e;
    float v = x[((size_t)(b * 64 + c)) * 4096 + n0 + r];
    int X = __float2int_rn(v * 1048576.0f);          // 2^20
    sq += (double)X * (double)X;
    int L0 = ((X + 128) & 255) - 128;
    int X1 = (X - L0) >> 8;
    int L1 = ((X1 + 128) & 255) - 128;
    int L2 = (X1 - L1) >> 8;
    v0[e] = (char)L0; v1[e] = (char)L1; v2[e] = (char)L2;
  }
  *(c16*)(blob + 0*5120 + r*80 + qc*16) = v0;
  *(c16*)(blob + 1*5120 + r*80 + qc*16) = v1;
  *(c16*)(blob + 2*5120 + r*80 + qc*16) = v2;
  sqp[qc][r] = sq;
  __syncthreads();
  if (t < 64)
    ws[WS_SQ + b * N_ + n0 + t] =
      (float)((sqp[0][t] + sqp[1][t] + sqp[2][t] + sqp[3][t]) * (1.0 / 1099511627776.0)); // 2^-40
}

// ===================== k1b: Y = wa.p, Z = wb.p =====================
__global__ __launch_bounds__(256) void k1b_yz(const float* __restrict__ x,
                                              const float* __restrict__ cw_, float* __restrict__ ws)
{
  __shared__ float P[64][65];
  __shared__ float waT[C_][O_];
  __shared__ float wbT[C_][O_];
  int b = blockIdx.y, n0 = blockIdx.x * 64;
  int t = threadIdx.x;
  {
    int o = t & 63, cb = t >> 6;
#pragma unroll
    for (int k = 0; k < 16; ++k) {
      int c = cb + 4 * k;
      float w1v = cw_[o * 128 + c];
      float w2v = cw_[o * 128 + 64 + c];
      waT[c][o] = w1v;
      wbT[c][o] = w2v - w1v;
    }
  }
  {
    int nl = t & 63, cw4 = t >> 6;
#pragma unroll
    for (int k = 0; k < 16; ++k) {
      int c = cw4 + 4 * k;
      P[nl][c] = x[((size_t)b * C_ + c) * N_ + n0 + nl];
    }
  }
  __syncthreads();
  int n = t & 63, og = t >> 6;
  v2f accY[8], accZ[8];
  const v2f zero2 = {0.f, 0.f};
#pragma unroll
  for (int i = 0; i < 8; ++i) { accY[i] = zero2; accZ[i] = zero2; }
  for (int c = 0; c < C_; ++c) {
    float p = P[n][c];
    v2f pp = {p, p};
    const v2f* wa2 = (const v2f*)&waT[c][og * 16];
    const v2f* wb2 = (const v2f*)&wbT[c][og * 16];
#pragma unroll
    for (int i = 0; i < 8; ++i) {
      accY[i] = __builtin_elementwise_fma(pp, wa2[i], accY[i]);
      accZ[i] = __builtin_elementwise_fma(pp, wb2[i], accZ[i]);
    }
  }
  size_t baseY = WS_Y + ((size_t)b * N_ + n0 + n) * O_ + og * 16;
  size_t baseZ = WS_Z + ((size_t)b * N_ + n0 + n) * O_ + og * 16;
#pragma unroll
  for (int i = 0; i < 8; ++i) {
    *(float2*)&ws[baseY + 2 * i] = make_float2(accY[i][0], accY[i][1]);
    *(float2*)&ws[baseZ + 2 * i] = make_float2(accZ[i][0], accZ[i][1]);
  }
}

// ===================== k2: i8-MFMA KNN + gather-max (256 thr, 64 q/block) ====
// LDS map (bytes):
//   Q blob   @0      (16384)
//   P dbuf   @16384  (2 x 16384)
//   pendk    @49152  (8192) | pendi @57344 (8192) | sqm @65536 (512)
// End-phase overlays: list2 @0 (40960), lmrg @40960 (20480), fidx @61440 (5120),
//   Mt @0 (64*69*4 = 17664)
#define K2_LDS 66560

__global__ __launch_bounds__(256, 2) void k2_knn(float* __restrict__ ws)
{
  extern __shared__ char lds_raw[];
  char*  Pdb   = lds_raw + 16384;
  float* pendk = (float*)(lds_raw + 49152);
  int*   pendi = (int*)(lds_raw + 57344);
  float* sqm   = (float*)(lds_raw + 65536);
  float2* list2 = (float2*)lds_raw;
  float2* lmrg  = (float2*)(lds_raw + 40960);
  int*    fidx  = (int*)(lds_raw + 61440);
  float*  Mt    = (float*)lds_raw;

  const int t = threadIdx.x;
  const int b = blockIdx.y;
  const int n0 = blockIdx.x * 64;
  const int w = t >> 6, l = t & 63, lo5 = l & 31, hi = l >> 5;
  const int qloc = (w & 1) * 32 + lo5;
  const int qg = n0 + qloc;
  const int mhalf = (w >> 1) * 32;
  const int rowm = mhalf + lo5;
  const int rowq = qloc;

  const char* i8b = (const char*)ws + WS_I8B;
  const float* sqg = ws + WS_SQ + (size_t)b * N_;

  // ---- prologue: stage this block's own Q blob
  {
    size_t qb = (size_t)(b * 64 + blockIdx.x) * 16384;
    gload16(i8b + qb +     0 + t * 16, lds_raw +     0 + t * 16);
    gload16(i8b + qb +  4096 + t * 16, lds_raw +  4096 + t * 16);
    gload16(i8b + qb +  8192 + t * 16, lds_raw +  8192 + t * 16);
    gload16(i8b + qb + 12288 + t * 16, lds_raw + 12288 + t * 16);
  }
  auto STAGE = [&](int bufn, int tile) {
    size_t blob = (size_t)(b * 64 + tile) * 16384;
    char* dst = Pdb + bufn * 16384;
    gload16(i8b + blob +     0 + t * 16, dst +     0 + t * 16);
    gload16(i8b + blob +  4096 + t * 16, dst +  4096 + t * 16);
    gload16(i8b + blob +  8192 + t * 16, dst +  8192 + t * 16);
    gload16(i8b + blob + 12288 + t * 16, dst + 12288 + t * 16);
    if (t < 16) gload16((const char*)(sqg + tile * 64) + t * 16, (char*)sqm + bufn * 256 + t * 16);
  };
  STAGE(0, 0);

  // ---- selection state
  float kd[K_]; int ki[K_];
#pragma unroll
  for (int i = 0; i < K_; ++i) { kd[i] = __builtin_inff(); ki[i] = 0; }
  float kd19 = __builtin_inff();
  int cnt = 0;

  auto flush = [&]() {
#pragma unroll 1
    for (int s = 0; s < 8; ++s) {
      if (__all(s >= cnt)) break;
      if (s < cnt) {
        float kx = pendk[s * 256 + t];
        int mx = pendi[s * 256 + t];
        if (kx < kd[K_ - 1]) {
          bool cc[K_];
#pragma unroll
          for (int i = 0; i < K_; ++i) cc[i] = kx < kd[i];
#pragma unroll
          for (int i = K_ - 1; i >= 1; --i) {
            kd[i] = cc[i-1] ? kd[i-1] : (cc[i] ? kx : kd[i]);
            ki[i] = cc[i-1] ? ki[i-1] : (cc[i] ? mx : ki[i]);
          }
          kd[0] = cc[0] ? kx : kd[0];
          ki[0] = cc[0] ? mx : ki[0];
        }
      }
    }
    cnt = 0;
    kd19 = kd[K_ - 1];
  };

  __syncthreads();

  // ---- Q fragments (loop-invariant): plane p, K-half kk
  i32x4 Bq[3][2];
#pragma unroll
  for (int p = 0; p < 3; ++p)
#pragma unroll
    for (int kk = 0; kk < 2; ++kk)
      Bq[p][kk] = *(const i32x4*)(lds_raw + p * 5120 + rowq * 80 + kk * 32 + hi * 16);

#pragma unroll 1
  for (int step = 0; step < 64; ++step) {
    const int buf = step & 1;
    if (step + 1 < 64) STAGE(buf ^ 1, step + 1);

    const char* Pb = Pdb + buf * 16384;
    i32x4 Ap[3][2];
#pragma unroll
    for (int p = 0; p < 3; ++p)
#pragma unroll
      for (int kk = 0; kk < 2; ++kk)
        Ap[p][kk] = *(const i32x4*)(Pb + p * 5120 + rowm * 80 + kk * 32 + hi * 16);

    i32x16 accA = {0,0,0,0,0,0,0,0,0,0,0,0,0,0,0,0};
    i32x16 accB = {0,0,0,0,0,0,0,0,0,0,0,0,0,0,0,0};
    i32x16 accC = {0,0,0,0,0,0,0,0,0,0,0,0,0,0,0,0};
    i32x16 accD = {0,0,0,0,0,0,0,0,0,0,0,0,0,0,0,0};
#pragma unroll
    for (int kk = 0; kk < 2; ++kk) {
      accA = __builtin_amdgcn_mfma_i32_32x32x32_i8(Ap[2][kk], Bq[2][kk], accA, 0, 0, 0);
      accB = __builtin_amdgcn_mfma_i32_32x32x32_i8(Ap[2][kk], Bq[1][kk], accB, 0, 0, 0);
      accB = __builtin_amdgcn_mfma_i32_32x32x32_i8(Ap[1][kk], Bq[2][kk], accB, 0, 0, 0);
      accC = __builtin_amdgcn_mfma_i32_32x32x32_i8(Ap[1][kk], Bq[1][kk], accC, 0, 0, 0);
      accC = __builtin_amdgcn_mfma_i32_32x32x32_i8(Ap[2][kk], Bq[0][kk], accC, 0, 0, 0);
      accC = __builtin_amdgcn_mfma_i32_32x32x32_i8(Ap[0][kk], Bq[2][kk], accC, 0, 0, 0);
      accD = __builtin_amdgcn_mfma_i32_32x32x32_i8(Ap[1][kk], Bq[0][kk], accD, 0, 0, 0);
      accD = __builtin_amdgcn_mfma_i32_32x32x32_i8(Ap[0][kk], Bq[1][kk], accD, 0, 0, 0);
    }

    // sq of this lane's 16 rows
    const float* sqt = sqm + buf * 64 + mhalf + 4 * hi;
    float4 s0 = *(const float4*)(sqt + 0);
    float4 s1 = *(const float4*)(sqt + 8);
    float4 s2 = *(const float4*)(sqt + 16);
    float4 s3 = *(const float4*)(sqt + 24);
    float sqa[16] = { s0.x,s0.y,s0.z,s0.w, s1.x,s1.y,s1.z,s1.w,
                      s2.x,s2.y,s2.z,s2.w, s3.x,s3.y,s3.z,s3.w };
    const int mbase = step * 64 + mhalf + 4 * hi;
#pragma unroll
    for (int r = 0; r < 16; ++r) {
      // key = sq_m - 2*dot = sq - (S22*2^-7 + S21*2^-15 + S14*2^-23 + S10*2^-31)
      float key = fmaf((float)accD[r], -4.656612873077393e-10f,
                  fmaf((float)accC[r], -1.1920928955078125e-7f,
                  fmaf((float)accB[r], -3.0517578125e-5f,
                  fmaf((float)accA[r], -0.0078125f, sqa[r]))));
      int m = mbase + (r & 3) + 8 * (r >> 2);
      if ((key < kd19) & (m != qg)) {
        pendk[cnt * 256 + t] = key;
        pendi[cnt * 256 + t] = m;
        ++cnt;
      }
      if ((r & 3) == 3) { if (__any(cnt >= 4)) flush(); }
    }
    __syncthreads();   // drains staged loads; protects buffer reuse
  }
  flush();
  __syncthreads();

  // ---- write per-lane sorted lists: query qloc, list j = (w>>1)*2 + hi
  {
    int j = (w >> 1) * 2 + hi;
#pragma unroll
    for (int s = 0; s < K_; ++s)
      list2[(size_t)(qloc * 4 + j) * K_ + s] = make_float2(kd[s], __int_as_float(ki[s]));
  }
  __syncthreads();
  // ---- merge stage 1: lists (0,1)->lmrg[2q], (2,3)->lmrg[2q+1]
  if (t < 128) {
    int q = t & 63, h = t >> 6;
    const float2* la = &list2[(size_t)(q * 4 + 2 * h) * K_];
    const float2* lb = &list2[(size_t)(q * 4 + 2 * h + 1) * K_];
    float2* lo = &lmrg[(size_t)(q * 2 + h) * K_];
    int ia = 0, ib2 = 0;
#pragma unroll 1
    for (int k = 0; k < K_; ++k) {
      float2 fa = la[ia];
      float2 fb = lb[ib2];
      bool ta = fa.x <= fb.x;
      lo[k] = ta ? fa : fb;
      ia += ta ? 1 : 0; ib2 += ta ? 0 : 1;
    }
  }
  __syncthreads();
  // ---- merge stage 2 -> final 20 indices
  if (t < 64) {
    const float2* la = &lmrg[(size_t)(t * 2) * K_];
    const float2* lb = &lmrg[(size_t)(t * 2 + 1) * K_];
    int ia = 0, ib2 = 0;
#pragma unroll 1
    for (int k = 0; k < K_; ++k) {
      float2 fa = la[ia];
      float2 fb = lb[ib2];
      bool ta = fa.x <= fb.x;
      fidx[t * K_ + k] = __float_as_int(ta ? fa.y : fb.y);
      ia += ta ? 1 : 0; ib2 += ta ? 0 : 1;
    }
  }
  __syncthreads();
  // ---- gather-max: M[b][o][n] = max_k Y[b][nbr][o] + Z[b][n][o]
  {
    int q = t & 63;
    int ob = (t >> 6) * 16;
    const float* __restrict__ Yb = ws + WS_Y + (size_t)b * N_ * O_;
    float4 mx[4];
#pragma unroll
    for (int i = 0; i < 4; ++i)
      mx[i] = make_float4(-__builtin_inff(), -__builtin_inff(), -__builtin_inff(), -__builtin_inff());
#pragma unroll 1
    for (int k = 0; k < K_; ++k) {
      int m = fidx[q * K_ + k];
      const float4* yr = (const float4*)&Yb[(size_t)m * O_ + ob];
#pragma unroll
      for (int i = 0; i < 4; ++i) {
        float4 v = yr[i];
        mx[i].x = fmaxf(mx[i].x, v.x);
        mx[i].y = fmaxf(mx[i].y, v.y);
        mx[i].z = fmaxf(mx[i].z, v.z);
        mx[i].w = fmaxf(mx[i].w, v.w);
      }
    }
    const float4* zr = (const float4*)&ws[WS_Z + ((size_t)b * N_ + n0 + q) * O_ + ob];
#pragma unroll
    for (int i = 0; i < 4; ++i) {
      float4 z = zr[i];
      Mt[q * 69 + ob + 4 * i + 0] = mx[i].x + z.x;
      Mt[q * 69 + ob + 4 * i + 1] = mx[i].y + z.y;
      Mt[q * 69 + ob + 4 * i + 2] = mx[i].z + z.z;
      Mt[q * 69 + ob + 4 * i + 3] = mx[i].w + z.w;
    }
  }
  __syncthreads();
  // ---- transpose-write to (B,O,N)
  {
    int o = t >> 2, seg = (t & 3) * 16;
    float* Mrow = ws + WS_M + ((size_t)b * O_ + o) * N_ + n0 + seg;
#pragma unroll
    for (int i = 0; i < 16; i += 4) {
      float4 wv;
      wv.x = Mt[(seg + i + 0) * 69 + o];
      wv.y = Mt[(seg + i + 1) * 69 + o];
      wv.z = Mt[(seg + i + 2) * 69 + o];
      wv.w = Mt[(seg + i + 3) * 69 + o];
      *(float4*)&Mrow[i] = wv;
    }
  }
}

// ===================== k3: per-(b,o) mean/var -> scale/shift =====================
__global__ __launch_bounds__(256) void k3_stats(float* __restrict__ ws)
{
  int bo = blockIdx.x;
  int t = threadIdx.x;
  const float4* Mr = (const float4*)&ws[WS_M + (size_t)bo * N_];
  float s = 0.f, ss = 0.f;
#pragma unroll
  for (int k = 0; k < 4; ++k) {
    float4 v = Mr[t + 256 * k];
    s  += v.x + v.y + v.z + v.w;
    ss += v.x * v.x + v.y * v.y + v.z * v.z + v.w * v.w;
  }
#pragma unroll
  for (int off = 32; off >= 1; off >>= 1) {
    s  += __shfl_down(s, off);
    ss += __shfl_down(ss, off);
  }
  __shared__ float red[8];
  int w = t >> 6;
  if ((t & 63) == 0) { red[w * 2] = s; red[w * 2 + 1] = ss; }
  __syncthreads();
  if (t == 0) {
    float S  = red[0] + red[2] + red[4] + red[6];
    float SS = red[1] + red[3] + red[5] + red[7];
    float mean = S / (float)N_;
    float var = fmaxf(SS / (float)N_ - mean * mean, 0.f);
    float g  = ws[WS_GAMMA + bo];
    float be = ws[WS_BETA + bo];
    float sc = g / sqrtf(var + EPS_);
    ws[WS_SCALE + bo] = sc;
    ws[WS_SHIFT + bo] = be - mean * sc;
  }
}

// ===================== k4: normalize + affine + relu =====================
__global__ __launch_bounds__(256) void k4_apply(const float* __restrict__ ws, float* __restrict__ out)
{
  int i4 = blockIdx.x * 256 + threadIdx.x;
  int bo = i4 >> 10;
  float sc = ws[WS_SCALE + bo], sh = ws[WS_SHIFT + bo];
  float4 v = *(const float4*)&ws[WS_M + (size_t)i4 * 4];
  float4 r;
  r.x = fmaxf(fmaf(v.x, sc, sh), 0.f);
  r.y = fmaxf(fmaf(v.y, sc, sh), 0.f);
  r.z = fmaxf(fmaf(v.z, sc, sh), 0.f);
  r.w = fmaxf(fmaf(v.w, sc, sh), 0.f);
  *(float4*)&out[(size_t)i4 * 4] = r;
}

extern "C" void kernel_launch(void* const* d_in, const int* in_sizes, int n_in,
                              void* d_out, int out_size, void* d_ws, size_t ws_size,
                              hipStream_t stream)
{
  const float* x   = (const float*)d_in[0];
  const float* emb = (const float*)d_in[1];
  const float* cw  = (const float*)d_in[2];
  const float* gw1 = (const float*)d_in[3];
  const float* gb1 = (const float*)d_in[4];
  const float* gw2 = (const float*)d_in[5];
  const float* gb2 = (const float*)d_in[6];
  const float* bw1 = (const float*)d_in[7];
  const float* bb1 = (const float*)d_in[8];
  const float* bw2 = (const float*)d_in[9];
  const float* bb2 = (const float*)d_in[10];
  float* ws  = (float*)d_ws;
  float* out = (float*)d_out;

  k0_mlp<<<1, 256, 0, stream>>>(emb, gw1, gb1, gw2, gb2, bw1, bb1, bw2, bb2, ws);
  k1a_split<<<dim3(64, 8), 256, 0, stream>>>(x, ws);
  k1b_yz<<<dim3(64, 8), 256, 0, stream>>>(x, cw, ws);
  k2_knn<<<dim3(64, 8), 256, K2_LDS, stream>>>(ws);
  k3_stats<<<512, 256, 0, stream>>>(ws);
  k4_apply<<<2048, 256, 0, stream>>>(ws, out);
}

// Round 7
// 508.242 us; speedup vs baseline: 2.4222x; 1.5793x over previous
//
#include <hip/hip_runtime.h>

#define B_ 8
#define C_ 64
#define N_ 4096
#define O_ 64
#define E_ 128
#define K_ 20
#define EPS_ 1e-5f

typedef float v2f __attribute__((ext_vector_type(2)));
typedef __attribute__((ext_vector_type(4)))  int  i32x4;
typedef __attribute__((ext_vector_type(16))) int  i32x16;
typedef __attribute__((ext_vector_type(16))) char c16;

// ---- workspace layout (float offsets) ----
#define WS_SQ    0                          // (B,N) |p_quant|^2 fp32
#define WS_Y     32768                      // (B,N,O)
#define WS_Z     (WS_Y + B_*N_*O_)          // (B,N,O)
#define WS_M     (WS_Z + B_*N_*O_)          // (B,O,N)
#define WS_GAMMA (WS_M + B_*N_*O_)
#define WS_BETA  (WS_GAMMA + 512)
#define WS_SCALE (WS_BETA + 512)
#define WS_SHIFT (WS_SCALE + 512)
#define WS_END_F (WS_SHIFT + 512)
#define WS_I8B   (WS_END_F * 4)             // BYTE offset of i8 limb blobs
// blob per (b,tile): 16384 B = 3 planes x (64 rows x 80 B) + 1024 pad
// plane p, row r, channel c: byte p*5120 + r*80 + c

// ===================== k0: domain MLPs -> gamma/beta =====================
__global__ __launch_bounds__(256) void k0_mlp(const float* __restrict__ emb,
    const float* __restrict__ gw1, const float* __restrict__ gb1,
    const float* __restrict__ gw2, const float* __restrict__ gb2,
    const float* __restrict__ bw1, const float* __restrict__ bb1,
    const float* __restrict__ bw2, const float* __restrict__ bb2,
    float* __restrict__ ws)
{
  __shared__ float s_emb[B_][E_];
  __shared__ float s_h[2][B_][E_];
  int t = threadIdx.x;
  for (int i = t; i < B_*E_; i += 256) s_emb[i >> 7][i & 127] = emb[i];
  __syncthreads();
  {
    int net = t >> 7, e = t & 127;
    const float* w1 = net ? bw1 : gw1;
    const float* b1 = net ? bb1 : gb1;
    float acc[B_];
#pragma unroll
    for (int b = 0; b < B_; ++b) acc[b] = 0.f;
    const float* row = w1 + e * E_;
    for (int j = 0; j < E_; j += 4) {
      float4 w = *(const float4*)(row + j);
#pragma unroll
      for (int b = 0; b < B_; ++b)
        acc[b] += s_emb[b][j]*w.x + s_emb[b][j+1]*w.y + s_emb[b][j+2]*w.z + s_emb[b][j+3]*w.w;
    }
    float bias = b1[e];
#pragma unroll
    for (int b = 0; b < B_; ++b) s_h[net][b][e] = fmaxf(acc[b] + bias, 0.f);
  }
  __syncthreads();
  for (int r = 0; r < 4; ++r) {
    int idx = t + 256 * r;
    int net = idx >> 9, b = (idx >> 6) & 7, o = idx & 63;
    const float* w2 = net ? bw2 : gw2;
    const float* b2 = net ? bb2 : gb2;
    const float* row = w2 + o * E_;
    float acc = 0.f;
    for (int e = 0; e < E_; e += 4) {
      float4 w = *(const float4*)(row + e);
      acc += s_h[net][b][e]*w.x + s_h[net][b][e+1]*w.y + s_h[net][b][e+2]*w.z + s_h[net][b][e+3]*w.w;
    }
    acc += b2[o];
    if (net == 0) ws[WS_GAMMA + b*O_ + o] = 1.f + acc;
    else          ws[WS_BETA  + b*O_ + o] = acc;
  }
}

// ===================== k1a: quantize x -> 3 i8 limb planes + exact |p|^2 ====
__global__ __launch_bounds__(256) void k1a_split(const float* __restrict__ x, float* __restrict__ ws)
{
  __shared__ double sqp[4][64];
  int b = blockIdx.y, T = blockIdx.x, n0 = T * 64;
  int t = threadIdx.x;
  int r = t & 63, qc = t >> 6;
  char* blob = (char*)ws + WS_I8B + (size_t)(b * 64 + T) * 16384;
  c16 v0, v1, v2;
  double sq = 0.0;
#pragma unroll
  for (int e = 0; e < 16; ++e) {
    int c = qc * 16 + e;
    float v = x[((size_t)(b * 64 + c)) * 4096 + n0 + r];
    int X = __float2int_rn(v * 1048576.0f);          // 2^20
    sq += (double)X * (double)X;
    int L0 = ((X + 128) & 255) - 128;
    int X1 = (X - L0) >> 8;
    int L1 = ((X1 + 128) & 255) - 128;
    int L2 = (X1 - L1) >> 8;
    v0[e] = (char)L0; v1[e] = (char)L1; v2[e] = (char)L2;
  }
  *(c16*)(blob + 0*5120 + r*80 + qc*16) = v0;
  *(c16*)(blob + 1*5120 + r*80 + qc*16) = v1;
  *(c16*)(blob + 2*5120 + r*80 + qc*16) = v2;
  sqp[qc][r] = sq;
  __syncthreads();
  if (t < 64)
    ws[WS_SQ + b * N_ + n0 + t] =
      (float)((sqp[0][t] + sqp[1][t] + sqp[2][t] + sqp[3][t]) * (1.0 / 1099511627776.0)); // 2^-40
}

// ===================== k1b: Y = wa.p, Z = wb.p (coalesced writes) ===========
// LDS: P @0 (64*65*4=16640) | waT @16640 (16384) | wbT @33024 (16384) = 49408
// overlay after compute: YT @0 (64*65*4), ZT @16640+... use stride-65 fp32
__global__ __launch_bounds__(256) void k1b_yz(const float* __restrict__ x,
                                              const float* __restrict__ cw_, float* __restrict__ ws)
{
  extern __shared__ char l1b[];
  float* P   = (float*)l1b;              // [64][65]
  float* waT = (float*)(l1b + 16640);    // [64][64]
  float* wbT = (float*)(l1b + 33024);    // [64][64]
  float* YT  = (float*)l1b;              // [64][65] overlay
  float* ZT  = (float*)(l1b + 16900);    // [64][65] overlay (float-offset 4225)
  int b = blockIdx.y, n0 = blockIdx.x * 64;
  int t = threadIdx.x;
  {
    int o = t & 63, cb = t >> 6;
#pragma unroll
    for (int k = 0; k < 16; ++k) {
      int c = cb + 4 * k;
      float w1v = cw_[o * 128 + c];
      float w2v = cw_[o * 128 + 64 + c];
      waT[c * 64 + o] = w1v;
      wbT[c * 64 + o] = w2v - w1v;
    }
  }
  {
    int nl = t & 63, cw4 = t >> 6;
#pragma unroll
    for (int k = 0; k < 16; ++k) {
      int c = cw4 + 4 * k;
      P[nl * 65 + c] = x[((size_t)b * C_ + c) * N_ + n0 + nl];
    }
  }
  __syncthreads();
  int n = t & 63, og = t >> 6;
  v2f accY[8], accZ[8];
  const v2f zero2 = {0.f, 0.f};
#pragma unroll
  for (int i = 0; i < 8; ++i) { accY[i] = zero2; accZ[i] = zero2; }
  for (int c = 0; c < C_; ++c) {
    float p = P[n * 65 + c];
    v2f pp = {p, p};
    const v2f* wa2 = (const v2f*)&waT[c * 64 + og * 16];
    const v2f* wb2 = (const v2f*)&wbT[c * 64 + og * 16];
#pragma unroll
    for (int i = 0; i < 8; ++i) {
      accY[i] = __builtin_elementwise_fma(pp, wa2[i], accY[i]);
      accZ[i] = __builtin_elementwise_fma(pp, wb2[i], accZ[i]);
    }
  }
  __syncthreads();   // P/waT/wbT dead; overlay YT/ZT
#pragma unroll
  for (int i = 0; i < 8; ++i) {
    YT[n * 65 + og * 16 + 2 * i + 0] = accY[i][0];
    YT[n * 65 + og * 16 + 2 * i + 1] = accY[i][1];
    ZT[n * 65 + og * 16 + 2 * i + 0] = accZ[i][0];
    ZT[n * 65 + og * 16 + 2 * i + 1] = accZ[i][1];
  }
  __syncthreads();
  {
    int nr = t >> 2, o0 = (t & 3) * 16;
    size_t gbase = ((size_t)b * N_ + n0 + nr) * O_ + o0;
#pragma unroll
    for (int j = 0; j < 16; j += 4) {
      float4 yv, zv;
      yv.x = YT[nr * 65 + o0 + j + 0]; yv.y = YT[nr * 65 + o0 + j + 1];
      yv.z = YT[nr * 65 + o0 + j + 2]; yv.w = YT[nr * 65 + o0 + j + 3];
      zv.x = ZT[nr * 65 + o0 + j + 0]; zv.y = ZT[nr * 65 + o0 + j + 1];
      zv.z = ZT[nr * 65 + o0 + j + 2]; zv.w = ZT[nr * 65 + o0 + j + 3];
      *(float4*)&ws[WS_Y + gbase + j] = yv;
      *(float4*)&ws[WS_Z + gbase + j] = zv;
    }
  }
}
#define K1B_LDS 49408

// ===================== k2: barrier-free i8-MFMA KNN + gather-max ============
// Main loop: NO LDS, NO barriers. A-frags + sq stream global->regs, ping-pong.
// LDS only for epilogue: list2 @0 (40960), lmrg @40960 (20480), fidx @61440
// (5120); Mt overlays @0 (64*69*4=17664). Total 66560 -> 2 blocks/CU.
#define K2_LDS 66560

struct FragT {
  i32x4 a00, a01, a10, a11, a20, a21;   // [plane][kk]
  float4 s0, s1, s2, s3;
};

__global__ __launch_bounds__(256, 2) void k2_knn(float* __restrict__ ws)
{
  extern __shared__ char lds_raw[];
  float2* list2 = (float2*)lds_raw;
  float2* lmrg  = (float2*)(lds_raw + 40960);
  int*    fidx  = (int*)(lds_raw + 61440);
  float*  Mt    = (float*)lds_raw;

  const int t = threadIdx.x;
  const int bid = blockIdx.x;
  const int b = bid & 7;                 // XCD-local batch (id%8 -> XCD)
  const int n0 = (bid >> 3) * 64;
  const int w = t >> 6, l = t & 63, lo5 = l & 31, hi = l >> 5;
  const int qloc = (w & 1) * 32 + lo5;
  const int qg = n0 + qloc;
  const int mhalf = (w >> 1) * 32;
  const int rowm = mhalf + lo5;

  const char* __restrict__ i8b = (const char*)ws + WS_I8B + (size_t)b * 64 * 16384;
  const float* __restrict__ sqg = ws + WS_SQ + (size_t)b * N_;

  // ---- Q fragments straight from global (loop-invariant)
  i32x4 Bq00, Bq01, Bq10, Bq11, Bq20, Bq21;
  {
    const char* qb = i8b + (size_t)(n0 >> 6) * 16384 + qloc * 80 + hi * 16;
    Bq00 = *(const i32x4*)(qb + 0);      Bq01 = *(const i32x4*)(qb + 32);
    Bq10 = *(const i32x4*)(qb + 5120);   Bq11 = *(const i32x4*)(qb + 5152);
    Bq20 = *(const i32x4*)(qb + 10240);  Bq21 = *(const i32x4*)(qb + 10272);
  }

  // ---- selection state: sorted top-20
  float kd[K_]; int ki[K_];
#pragma unroll
  for (int i = 0; i < K_; ++i) { kd[i] = __builtin_inff(); ki[i] = 0; }
  float kd19 = __builtin_inff();

  auto LOADF = [&](FragT& F, int tile) {
    const char* bb = i8b + (size_t)tile * 16384 + rowm * 80 + hi * 16;
    F.a00 = *(const i32x4*)(bb + 0);      F.a01 = *(const i32x4*)(bb + 32);
    F.a10 = *(const i32x4*)(bb + 5120);   F.a11 = *(const i32x4*)(bb + 5152);
    F.a20 = *(const i32x4*)(bb + 10240);  F.a21 = *(const i32x4*)(bb + 10272);
    const float* sp = sqg + tile * 64 + mhalf + 4 * hi;
    F.s0 = *(const float4*)(sp + 0);  F.s1 = *(const float4*)(sp + 8);
    F.s2 = *(const float4*)(sp + 16); F.s3 = *(const float4*)(sp + 24);
  };

  auto BODY = [&](const FragT& F, int step) {
    i32x16 accA = {0,0,0,0,0,0,0,0,0,0,0,0,0,0,0,0};
    i32x16 accB = {0,0,0,0,0,0,0,0,0,0,0,0,0,0,0,0};
    i32x16 accC = {0,0,0,0,0,0,0,0,0,0,0,0,0,0,0,0};
    i32x16 accD = {0,0,0,0,0,0,0,0,0,0,0,0,0,0,0,0};
    accA = __builtin_amdgcn_mfma_i32_32x32x32_i8(F.a20, Bq20, accA, 0, 0, 0);
    accB = __builtin_amdgcn_mfma_i32_32x32x32_i8(F.a20, Bq10, accB, 0, 0, 0);
    accC = __builtin_amdgcn_mfma_i32_32x32x32_i8(F.a10, Bq10, accC, 0, 0, 0);
    accD = __builtin_amdgcn_mfma_i32_32x32x32_i8(F.a10, Bq00, accD, 0, 0, 0);
    accA = __builtin_amdgcn_mfma_i32_32x32x32_i8(F.a21, Bq21, accA, 0, 0, 0);
    accB = __builtin_amdgcn_mfma_i32_32x32x32_i8(F.a10, Bq20, accB, 0, 0, 0);
    accC = __builtin_amdgcn_mfma_i32_32x32x32_i8(F.a20, Bq00, accC, 0, 0, 0);
    accD = __builtin_amdgcn_mfma_i32_32x32x32_i8(F.a00, Bq10, accD, 0, 0, 0);
    accB = __builtin_amdgcn_mfma_i32_32x32x32_i8(F.a21, Bq11, accB, 0, 0, 0);
    accC = __builtin_amdgcn_mfma_i32_32x32x32_i8(F.a00, Bq20, accC, 0, 0, 0);
    accD = __builtin_amdgcn_mfma_i32_32x32x32_i8(F.a11, Bq01, accD, 0, 0, 0);
    accB = __builtin_amdgcn_mfma_i32_32x32x32_i8(F.a11, Bq21, accB, 0, 0, 0);
    accC = __builtin_amdgcn_mfma_i32_32x32x32_i8(F.a11, Bq11, accC, 0, 0, 0);
    accD = __builtin_amdgcn_mfma_i32_32x32x32_i8(F.a01, Bq11, accD, 0, 0, 0);
    accC = __builtin_amdgcn_mfma_i32_32x32x32_i8(F.a21, Bq01, accC, 0, 0, 0);
    accC = __builtin_amdgcn_mfma_i32_32x32x32_i8(F.a01, Bq21, accC, 0, 0, 0);

    float sqa[16] = { F.s0.x,F.s0.y,F.s0.z,F.s0.w, F.s1.x,F.s1.y,F.s1.z,F.s1.w,
                      F.s2.x,F.s2.y,F.s2.z,F.s2.w, F.s3.x,F.s3.y,F.s3.z,F.s3.w };
    const int mbase = step * 64 + mhalf + 4 * hi;
#pragma unroll
    for (int r = 0; r < 16; ++r) {
      float key = fmaf((float)accD[r], -4.656612873077393e-10f,
                  fmaf((float)accC[r], -1.1920928955078125e-7f,
                  fmaf((float)accB[r], -3.0517578125e-5f,
                  fmaf((float)accA[r], -0.0078125f, sqa[r]))));
      int m = mbase + (r & 3) + 8 * (r >> 2);
      bool want = (key < kd19) & (m != qg);
      if (__any(want)) {
        if (want) {
          bool cc[K_];
#pragma unroll
          for (int i = 0; i < K_; ++i) cc[i] = key < kd[i];
#pragma unroll
          for (int i = K_ - 1; i >= 1; --i) {
            kd[i] = cc[i-1] ? kd[i-1] : (cc[i] ? key : kd[i]);
            ki[i] = cc[i-1] ? ki[i-1] : (cc[i] ? m : ki[i]);
          }
          kd[0] = cc[0] ? key : kd[0];
          ki[0] = cc[0] ? m : ki[0];
        }
        kd19 = kd[K_ - 1];
      }
    }
  };

  // ---- barrier-free main loop: register ping-pong, 1 tile prefetch ahead
  FragT FA, FB;
  LOADF(FA, 0);
#pragma unroll 1
  for (int s = 0; s < 64; s += 2) {
    LOADF(FB, s + 1);
    BODY(FA, s);
    LOADF(FA, (s + 2 < 64) ? (s + 2) : 63);
    BODY(FB, s + 1);
  }

  // ---- write per-lane sorted lists: query qloc, list j = (w>>1)*2 + hi
  {
    int j = (w >> 1) * 2 + hi;
#pragma unroll
    for (int s = 0; s < K_; ++s)
      list2[(size_t)(qloc * 4 + j) * K_ + s] = make_float2(kd[s], __int_as_float(ki[s]));
  }
  __syncthreads();
  // ---- merge stage 1: lists (0,1)->lmrg[2q], (2,3)->lmrg[2q+1]
  if (t < 128) {
    int q = t & 63, h = t >> 6;
    const float2* la = &list2[(size_t)(q * 4 + 2 * h) * K_];
    const float2* lb = &list2[(size_t)(q * 4 + 2 * h + 1) * K_];
    float2* lo = &lmrg[(size_t)(q * 2 + h) * K_];
    int ia = 0, ib2 = 0;
#pragma unroll 1
    for (int k = 0; k < K_; ++k) {
      float2 fa = la[ia];
      float2 fb = lb[ib2];
      bool ta = fa.x <= fb.x;
      lo[k] = ta ? fa : fb;
      ia += ta ? 1 : 0; ib2 += ta ? 0 : 1;
    }
  }
  __syncthreads();
  // ---- merge stage 2 -> final 20 indices
  if (t < 64) {
    const float2* la = &lmrg[(size_t)(t * 2) * K_];
    const float2* lb = &lmrg[(size_t)(t * 2 + 1) * K_];
    int ia = 0, ib2 = 0;
#pragma unroll 1
    for (int k = 0; k < K_; ++k) {
      float2 fa = la[ia];
      float2 fb = lb[ib2];
      bool ta = fa.x <= fb.x;
      fidx[t * K_ + k] = __float_as_int(ta ? fa.y : fb.y);
      ia += ta ? 1 : 0; ib2 += ta ? 0 : 1;
    }
  }
  __syncthreads();
  // ---- gather-max: M[b][o][n] = max_k Y[b][nbr][o] + Z[b][n][o]
  {
    int q = t & 63;
    int ob = (t >> 6) * 16;
    const float* __restrict__ Yb = ws + WS_Y + (size_t)b * N_ * O_;
    float4 mx[4];
#pragma unroll
    for (int i = 0; i < 4; ++i)
      mx[i] = make_float4(-__builtin_inff(), -__builtin_inff(), -__builtin_inff(), -__builtin_inff());
#pragma unroll 1
    for (int k = 0; k < K_; ++k) {
      int m = fidx[q * K_ + k];
      const float4* yr = (const float4*)&Yb[(size_t)m * O_ + ob];
#pragma unroll
      for (int i = 0; i < 4; ++i) {
        float4 v = yr[i];
        mx[i].x = fmaxf(mx[i].x, v.x);
        mx[i].y = fmaxf(mx[i].y, v.y);
        mx[i].z = fmaxf(mx[i].z, v.z);
        mx[i].w = fmaxf(mx[i].w, v.w);
      }
    }
    const float4* zr = (const float4*)&ws[WS_Z + ((size_t)b * N_ + n0 + q) * O_ + ob];
#pragma unroll
    for (int i = 0; i < 4; ++i) {
      float4 z = zr[i];
      Mt[q * 69 + ob + 4 * i + 0] = mx[i].x + z.x;
      Mt[q * 69 + ob + 4 * i + 1] = mx[i].y + z.y;
      Mt[q * 69 + ob + 4 * i + 2] = mx[i].z + z.z;
      Mt[q * 69 + ob + 4 * i + 3] = mx[i].w + z.w;
    }
  }
  __syncthreads();
  // ---- transpose-write to (B,O,N)
  {
    int o = t >> 2, seg = (t & 3) * 16;
    float* Mrow = ws + WS_M + ((size_t)b * O_ + o) * N_ + n0 + seg;
#pragma unroll
    for (int i = 0; i < 16; i += 4) {
      float4 wv;
      wv.x = Mt[(seg + i + 0) * 69 + o];
      wv.y = Mt[(seg + i + 1) * 69 + o];
      wv.z = Mt[(seg + i + 2) * 69 + o];
      wv.w = Mt[(seg + i + 3) * 69 + o];
      *(float4*)&Mrow[i] = wv;
    }
  }
}

// ===================== k3: per-(b,o) mean/var -> scale/shift =====================
__global__ __launch_bounds__(256) void k3_stats(float* __restrict__ ws)
{
  int bo = blockIdx.x;
  int t = threadIdx.x;
  const float4* Mr = (const float4*)&ws[WS_M + (size_t)bo * N_];
  float s = 0.f, ss = 0.f;
#pragma unroll
  for (int k = 0; k < 4; ++k) {
    float4 v = Mr[t + 256 * k];
    s  += v.x + v.y + v.z + v.w;
    ss += v.x * v.x + v.y * v.y + v.z * v.z + v.w * v.w;
  }
#pragma unroll
  for (int off = 32; off >= 1; off >>= 1) {
    s  += __shfl_down(s, off);
    ss += __shfl_down(ss, off);
  }
  __shared__ float red[8];
  int w = t >> 6;
  if ((t & 63) == 0) { red[w * 2] = s; red[w * 2 + 1] = ss; }
  __syncthreads();
  if (t == 0) {
    float S  = red[0] + red[2] + red[4] + red[6];
    float SS = red[1] + red[3] + red[5] + red[7];
    float mean = S / (float)N_;
    float var = fmaxf(SS / (float)N_ - mean * mean, 0.f);
    float g  = ws[WS_GAMMA + bo];
    float be = ws[WS_BETA + bo];
    float sc = g / sqrtf(var + EPS_);
    ws[WS_SCALE + bo] = sc;
    ws[WS_SHIFT + bo] = be - mean * sc;
  }
}

// ===================== k4: normalize + affine + relu =====================
__global__ __launch_bounds__(256) void k4_apply(const float* __restrict__ ws, float* __restrict__ out)
{
  int i4 = blockIdx.x * 256 + threadIdx.x;
  int bo = i4 >> 10;
  float sc = ws[WS_SCALE + bo], sh = ws[WS_SHIFT + bo];
  float4 v = *(const float4*)&ws[WS_M + (size_t)i4 * 4];
  float4 r;
  r.x = fmaxf(fmaf(v.x, sc, sh), 0.f);
  r.y = fmaxf(fmaf(v.y, sc, sh), 0.f);
  r.z = fmaxf(fmaf(v.z, sc, sh), 0.f);
  r.w = fmaxf(fmaf(v.w, sc, sh), 0.f);
  *(float4*)&out[(size_t)i4 * 4] = r;
}

extern "C" void kernel_launch(void* const* d_in, const int* in_sizes, int n_in,
                              void* d_out, int out_size, void* d_ws, size_t ws_size,
                              hipStream_t stream)
{
  const float* x   = (const float*)d_in[0];
  const float* emb = (const float*)d_in[1];
  const float* cw  = (const float*)d_in[2];
  const float* gw1 = (const float*)d_in[3];
  const float* gb1 = (const float*)d_in[4];
  const float* gw2 = (const float*)d_in[5];
  const float* gb2 = (const float*)d_in[6];
  const float* bw1 = (const float*)d_in[7];
  const float* bb1 = (const float*)d_in[8];
  const float* bw2 = (const float*)d_in[9];
  const float* bb2 = (const float*)d_in[10];
  float* ws  = (float*)d_ws;
  float* out = (float*)d_out;

  k0_mlp<<<1, 256, 0, stream>>>(emb, gw1, gb1, gw2, gb2, bw1, bb1, bw2, bb2, ws);
  k1a_split<<<dim3(64, 8), 256, 0, stream>>>(x, ws);
  k1b_yz<<<dim3(64, 8), 256, K1B_LDS, stream>>>(x, cw, ws);
  k2_knn<<<512, 256, K2_LDS, stream>>>(ws);
  k3_stats<<<512, 256, 0, stream>>>(ws);
  k4_apply<<<2048, 256, 0, stream>>>(ws, out);
}